// Round 9
// baseline (314.162 us; speedup 1.0000x reference)
//
#include <hip/hip_runtime.h>
#include <math.h>

#define ROWS 100352        // B * NW * N = 2*512*98
#define EPSL 1e-5f
#define SCALE_Q 0.17677669529663687f   // 32^-0.5

typedef __attribute__((ext_vector_type(8))) short bf16x8;
typedef __attribute__((ext_vector_type(4))) float f32x4;

__device__ __forceinline__ unsigned short f2b(float f) {
  union { float f; unsigned int u; } a; a.f = f;
  unsigned int u = a.u;
  return (unsigned short)((u + 0x7FFF + ((u >> 16) & 1)) >> 16);  // RNE
}
__device__ __forceinline__ unsigned cvtpk(float lo, float hi) {
  unsigned r;
  asm volatile("v_cvt_pk_bf16_f32 %0, %1, %2" : "=v"(r) : "v"(lo), "v"(hi));
  return r;
}

// partition-row -> x flat spatial index (applies shift)
__device__ __forceinline__ int map_row(int r) {
  int t = r;
  int tw = t % 7; t /= 7;
  int th = t % 7; t /= 7;
  int td = t & 1;  t >>= 1;
  int zw = t & 7;  t >>= 3;
  int zh = t & 7;  t >>= 3;
  int zd = t & 7;  int bb = t >> 3;
  int d = zd * 2 + td;
  int h = zh * 7 + th;
  int w = zw * 7 + tw;
  int sd = (d + 1) & 15;
  int sh = h + 3; if (sh >= 56) sh -= 56;
  int sw = w + 3; if (sw >= 56) sw -= 56;
  return ((bb * 16 + sd) * 56 + sh) * 56 + sw;
}

// weight transposes (W[K][N] -> Wt[N][K] bf16); SCALE folded into Q cols of qkvT;
// LN2 gamma folded into fc1T.
__global__ __launch_bounds__(256) void k_prep_all(
    const float* __restrict__ qkv_w, unsigned short* __restrict__ qkvT,
    const float* __restrict__ proj_w, unsigned short* __restrict__ projT,
    const float* __restrict__ fc1_w, unsigned short* __restrict__ fc1T,
    const float* __restrict__ fc2_w, unsigned short* __restrict__ fc2T,
    const float* __restrict__ n2g)
{
  int b = blockIdx.x, tid = threadIdx.x;
  if (b < 192) {                      // qkvT: [384][128]
    int id = b * 256 + tid;
    int n = id >> 7, k = id & 127;
    float v = qkv_w[(size_t)k * 384 + n];
    if (n < 128) v *= SCALE_Q;        // Q columns pre-scaled
    qkvT[id] = f2b(v);
  } else if (b < 256) {               // projT: [128][128]
    int id = (b - 192) * 256 + tid;
    int n = id >> 7, k = id & 127;
    projT[id] = f2b(proj_w[(size_t)k * 128 + n]);
  } else if (b < 512) {               // fc1T: [512][128], gamma folded
    int id = (b - 256) * 256 + tid;
    int n = id >> 7, k = id & 127;
    fc1T[id] = f2b(fc1_w[(size_t)k * 512 + n] * n2g[k]);
  } else {                            // fc2T: [128][512]
    int id = (b - 512) * 256 + tid;
    int n = id >> 9, k = id & 511;
    fc2T[id] = f2b(fc2_w[(size_t)k * 128 + n]);
  }
}

// b1p[h] = fc1_b[h] + sum_k n2b[k] * fc1_w[k][h]   (LN2 beta folded)
__global__ __launch_bounds__(256) void k_prep_b1(
    const float* __restrict__ fc1_b, const float* __restrict__ n2b,
    const float* __restrict__ fc1_w, float* __restrict__ b1p)
{
  int h = blockIdx.x * 256 + threadIdx.x;
  if (h >= 512) return;
  float acc = fc1_b[h];
  for (int k = 0; k < 128; ++k) acc += n2b[k] * fc1_w[(size_t)k * 512 + h];
  b1p[h] = acc;
}

// biasC[wm][h][rt][ct][lane][4] : rel-bias + shift-mask + pad, in MFMA C-frag layout.
__global__ __launch_bounds__(256) void k_prep_biasC(
    const int* __restrict__ relidx, const float* __restrict__ rtab,
    float* __restrict__ biasC)
{
  int id = blockIdx.x * 256 + threadIdx.x;   // 8*4*8*7*64 = 114688
  int l  = id & 63;  int t = id >> 6;
  int ct = t % 7;    t /= 7;
  int rt = t & 7;    t >>= 3;
  int h  = t & 3;    int wm = t >> 2;
  int n0 = rt*16 + ((l >> 4) << 2);
  int m  = ct*16 + (l & 15);
  float4 v;
  float* vp = &v.x;
  int cm = 0;
  if (m < 98)
    cm = (m >= 49 ? 1 : 0) | ((m % 49) >= 28 ? 2 : 0) | ((m % 7) >= 4 ? 4 : 0);
  #pragma unroll
  for (int r = 0; r < 4; ++r) {
    int n = n0 + r;
    float val;
    if (m >= 98) val = -10000.f;
    else if (n >= 98) val = 0.f;
    else {
      val = rtab[relidx[n*98 + m]*4 + h];
      int cn = (n >= 49 ? 1 : 0) | ((n % 49) >= 28 ? 2 : 0) | ((n % 7) >= 4 ? 4 : 0);
      if ((cn ^ cm) & wm) val -= 100.f;
    }
    vp[r] = val;
  }
  *(float4*)(biasC + (size_t)id*4) = v;
}

// ---- fused LN1 (+shift/partition gather) + qkv GEMM ----
__global__ __launch_bounds__(256) void k_qkv(
    const float* __restrict__ x, const float* __restrict__ g,
    const float* __restrict__ bta, const unsigned short* __restrict__ Wt,
    const float* __restrict__ bias, unsigned short* __restrict__ out)
{
  __shared__ unsigned short As[128 * 136];
  int tid = threadIdx.x;
  int row0 = blockIdx.x * 128;
  {
    int grp = tid >> 5, lane = tid & 31;
    float4 gv = *(const float4*)(g + lane*4);
    float4 bv = *(const float4*)(bta + lane*4);
    #pragma unroll
    for (int p = 0; p < 16; ++p) {
      int r = p * 8 + grp;
      size_t src = (size_t)map_row(row0 + r);
      float4 v = *(const float4*)(x + src * 128 + lane * 4);
      float s  = v.x + v.y + v.z + v.w;
      float ss = v.x*v.x + v.y*v.y + v.z*v.z + v.w*v.w;
      #pragma unroll
      for (int o = 16; o; o >>= 1) {
        s  += __shfl_xor(s,  o, 32);
        ss += __shfl_xor(ss, o, 32);
      }
      float mu   = s * (1.f/128.f);
      float rstd = rsqrtf(ss * (1.f/128.f) - mu*mu + EPSL);
      ushort4 o4;
      o4.x = f2b((v.x-mu)*rstd*gv.x + bv.x);
      o4.y = f2b((v.y-mu)*rstd*gv.y + bv.y);
      o4.z = f2b((v.z-mu)*rstd*gv.z + bv.z);
      o4.w = f2b((v.w-mu)*rstd*gv.w + bv.w);
      *(ushort4*)&As[r*136 + lane*4] = o4;
    }
  }
  __syncthreads();
  int l = tid & 63, w = tid >> 6;
  int wr = (w >> 1) * 64, wc = (w & 1) * 64;
  int fr = l & 15, gq = l >> 4, fk = gq * 8;
  for (int c = 0; c < 3; ++c) {
    int col0 = c * 128;
    float bmul = (c == 0) ? SCALE_Q : 1.f;   // Q bias pre-scaled to match weights
    f32x4 acc[4][4] = {};
    #pragma unroll
    for (int ks = 0; ks < 128; ks += 32) {
      bf16x8 af[4], bv[4];
      #pragma unroll
      for (int n = 0; n < 4; ++n)
        bv[n] = *(const bf16x8*)(Wt + (size_t)(col0 + wc + n*16 + fr)*128 + ks + fk);
      #pragma unroll
      for (int m = 0; m < 4; ++m)
        af[m] = *(bf16x8*)&As[(wr + m*16 + fr)*136 + ks + fk];
      #pragma unroll
      for (int m = 0; m < 4; ++m)
        #pragma unroll
        for (int n = 0; n < 4; ++n)
          acc[m][n] = __builtin_amdgcn_mfma_f32_16x16x32_bf16(af[m], bv[n], acc[m][n], 0, 0, 0);
    }
    #pragma unroll
    for (int m = 0; m < 4; ++m)
      #pragma unroll
      for (int r = 0; r < 4; ++r) {
        int grow = row0 + wr + m*16 + gq*4 + r;
        #pragma unroll
        for (int n = 0; n < 4; ++n) {
          int col = col0 + wc + n*16 + fr;
          out[(size_t)grow*384 + col] = f2b(acc[m][n][r] + bias[col]*bmul);
        }
      }
  }
}

// MFMA attention: bias/mask/scale baked into biasC (C-frag layout).
__global__ __launch_bounds__(256, 4) void k_attn_mfma(
    const unsigned short* __restrict__ qkv,     // (ROWS, 384) bf16, Q pre-scaled
    const float* __restrict__ biasC,            // [8][4][8][7][64][4] f32
    unsigned short* __restrict__ o_part)        // (ROWS, 128) bf16
{
  __shared__ unsigned short Vt[32 * 136];   // [d][m]
  __shared__ unsigned short Pb[128 * 120];  // [n][m]
  int tid  = threadIdx.x;
  int head = blockIdx.x & 3;
  int win  = blockIdx.x >> 2;
  int widx = win & 511;
  int wm = ((widx >> 6) == 7 ? 1 : 0) | (((widx >> 3) & 7) == 7 ? 2 : 0)
         | ((widx & 7) == 7 ? 4 : 0);
  const unsigned short* base = qkv + (size_t)win * 98 * 384 + head * 32;

  for (int it = tid; it < 32 * 128; it += 256) {
    int d = it & 31, m = it >> 5;
    unsigned short v = 0;
    if (m < 98) v = base[m*384 + 256 + d];
    Vt[d*136 + m] = v;
  }
  for (int it = tid; it < 128 * 8; it += 256) {
    int n = it >> 3, c2 = 112 + (it & 7);
    Pb[n*120 + c2] = 0;
  }

  int l = tid & 63, w = tid >> 6;
  int fr = l & 15, g = l >> 4, fk = g * 8;
  bf16x8 zero8 = {0,0,0,0,0,0,0,0};

  bf16x8 aq[2];
  #pragma unroll
  for (int lt = 0; lt < 2; ++lt) {
    int row = (w*2 + lt)*16 + fr;
    aq[lt] = (row < 98) ? *(const bf16x8*)(base + row*384 + fk) : zero8;
  }

  const float* bcb = biasC + (size_t)(wm*4 + head) * 8 * 7 * 256;
  f32x4 S[2][7];
  #pragma unroll
  for (int ct = 0; ct < 7; ++ct) {
    int m = ct*16 + fr;
    bf16x8 kb = (m < 98) ? *(const bf16x8*)(base + m*384 + 128 + fk) : zero8;
    #pragma unroll
    for (int lt = 0; lt < 2; ++lt) {
      f32x4 bc = *(const f32x4*)(bcb + ((w*2 + lt)*7 + ct)*256 + l*4);
      S[lt][ct] = __builtin_amdgcn_mfma_f32_16x16x32_bf16(aq[lt], kb, bc, 0, 0, 0);
    }
  }

  #pragma unroll
  for (int lt = 0; lt < 2; ++lt) {
    #pragma unroll
    for (int r = 0; r < 4; ++r) {
      float mx = S[lt][0][r];
      #pragma unroll
      for (int ct = 1; ct < 7; ++ct) mx = fmaxf(mx, S[lt][ct][r]);
      #pragma unroll
      for (int o = 8; o; o >>= 1) mx = fmaxf(mx, __shfl_xor(mx, o));
      float e[7], sum = 0.f;
      #pragma unroll
      for (int ct = 0; ct < 7; ++ct) { e[ct] = __expf(S[lt][ct][r] - mx); sum += e[ct]; }
      #pragma unroll
      for (int o = 8; o; o >>= 1) sum += __shfl_xor(sum, o);
      float inv = 1.f / sum;
      #pragma unroll
      for (int ct = 0; ct < 7; ++ct) S[lt][ct][r] = e[ct] * inv;
    }
  }

  #pragma unroll
  for (int lt = 0; lt < 2; ++lt)
    #pragma unroll
    for (int ct = 0; ct < 7; ++ct) {
      int m = ct*16 + fr;
      #pragma unroll
      for (int r = 0; r < 4; ++r) {
        int n = w*32 + lt*16 + g*4 + r;
        Pb[n*120 + m] = f2b(S[lt][ct][r]);
      }
    }
  __syncthreads();

  f32x4 O[2][2] = {};
  #pragma unroll
  for (int ks = 0; ks < 4; ++ks) {
    bf16x8 ap[2], bv[2];
    #pragma unroll
    for (int lt = 0; lt < 2; ++lt) {
      int rowoff = ((w*2 + lt)*16 + fr)*120;
      if (ks < 3) ap[lt] = *(bf16x8*)&Pb[rowoff + ks*32 + fk];
      else        ap[lt] = (g < 2) ? *(bf16x8*)&Pb[rowoff + 96 + fk] : zero8;
    }
    #pragma unroll
    for (int vt = 0; vt < 2; ++vt)
      bv[vt] = *(bf16x8*)&Vt[(vt*16 + fr)*136 + ks*32 + fk];
    #pragma unroll
    for (int lt = 0; lt < 2; ++lt)
      #pragma unroll
      for (int vt = 0; vt < 2; ++vt)
        O[lt][vt] = __builtin_amdgcn_mfma_f32_16x16x32_bf16(ap[lt], bv[vt], O[lt][vt], 0, 0, 0);
  }

  #pragma unroll
  for (int lt = 0; lt < 2; ++lt)
    #pragma unroll
    for (int r = 0; r < 4; ++r) {
      int n = w*32 + lt*16 + g*4 + r;
      if (n < 98) {
        unsigned short* orow = o_part + ((size_t)win*98 + n)*128 + head*32;
        #pragma unroll
        for (int vt = 0; vt < 2; ++vt)
          orow[vt*16 + fr] = f2b(O[lt][vt][r]);
      }
    }
}

// ---- proj GEMM + window-reverse/unshift scatter + residual ----
__global__ __launch_bounds__(256) void k_proj(
    const unsigned short* __restrict__ A,
    const unsigned short* __restrict__ Wt,
    const float* __restrict__ bias,
    const float* __restrict__ Xres, float* __restrict__ Cf)
{
  __shared__ unsigned short As[128 * 136];
  int tid = threadIdx.x;
  int row0 = blockIdx.x * 128;
  #pragma unroll
  for (int i = 0; i < 8; ++i) {
    int chunk = i * 256 + tid;
    int rr = chunk >> 4, off = (chunk & 15) * 8;
    *(uint4*)&As[rr*136 + off] = *(const uint4*)(A + (size_t)(row0+rr)*128 + off);
  }
  __syncthreads();
  int l = tid & 63, w = tid >> 6;
  int wr = (w >> 1) * 64, wc = (w & 1) * 64;
  int fr = l & 15, gq = l >> 4, fk = gq * 8;
  f32x4 acc[4][4] = {};
  #pragma unroll
  for (int ks = 0; ks < 128; ks += 32) {
    bf16x8 af[4], bv[4];
    #pragma unroll
    for (int n = 0; n < 4; ++n)
      bv[n] = *(const bf16x8*)(Wt + (size_t)(wc + n*16 + fr)*128 + ks + fk);
    #pragma unroll
    for (int m = 0; m < 4; ++m)
      af[m] = *(bf16x8*)&As[(wr + m*16 + fr)*136 + ks + fk];
    #pragma unroll
    for (int m = 0; m < 4; ++m)
      #pragma unroll
      for (int n = 0; n < 4; ++n)
        acc[m][n] = __builtin_amdgcn_mfma_f32_16x16x32_bf16(af[m], bv[n], acc[m][n], 0, 0, 0);
  }
  #pragma unroll
  for (int m = 0; m < 4; ++m)
    #pragma unroll
    for (int r = 0; r < 4; ++r) {
      int grow = row0 + wr + m*16 + gq*4 + r;
      size_t dst = (size_t)map_row(grow);
      #pragma unroll
      for (int n = 0; n < 4; ++n) {
        int col = wc + n*16 + fr;
        Cf[dst*128 + col] = acc[m][n][r] + bias[col] + Xres[dst*128 + col];
      }
    }
}

// ---- fused LN2 + fc1 + gelu + fc2 + residual ; ZERO LDS, ZERO barriers ----
// 4 waves/block, each wave owns 32 tokens (2 token-tiles). Swapped-operand fc1
// (tokens on lanes), in-register P transpose via cvt_pk + ds_bpermute.
__global__ __launch_bounds__(256, 3) void k_mlp(
    float* __restrict__ xio,
    const unsigned short* __restrict__ W1t,   // [512][128], gamma folded
    const float* __restrict__ b1p,            // [512], beta folded
    const unsigned short* __restrict__ W2t,   // [128][512]
    const float* __restrict__ b2)
{
  int tid = threadIdx.x;
  int l = tid & 63, w = tid >> 6;
  int i = l & 15, gl = l >> 4;
  int fk = gl * 8;
  int tok0 = blockIdx.x * 128 + w * 32;

  // bpermute lane patterns (byte offsets)
  int idx0 = (((l >> 4) & 1) * 32 + i) * 4;
  int idx1 = idx0 + 64;
  bool hiHalf = (l >= 32);

  // ---- load + LN (mean/rstd only; gamma/beta folded into W1/b1) ----
  bf16x8 atok[2][4];
  #pragma unroll
  for (int t = 0; t < 2; ++t) {
    const float* row = xio + (size_t)(tok0 + t*16 + i) * 128;
    float v[4][8];
    float s = 0.f, ss = 0.f;
    #pragma unroll
    for (int ks = 0; ks < 4; ++ks) {
      float4 v0 = *(const float4*)(row + ks*32 + fk);
      float4 v1 = *(const float4*)(row + ks*32 + fk + 4);
      v[ks][0]=v0.x; v[ks][1]=v0.y; v[ks][2]=v0.z; v[ks][3]=v0.w;
      v[ks][4]=v1.x; v[ks][5]=v1.y; v[ks][6]=v1.z; v[ks][7]=v1.w;
      s += v0.x+v0.y+v0.z+v0.w + v1.x+v1.y+v1.z+v1.w;
      ss += v0.x*v0.x+v0.y*v0.y+v0.z*v0.z+v0.w*v0.w
          + v1.x*v1.x+v1.y*v1.y+v1.z*v1.z+v1.w*v1.w;
    }
    s  += __shfl_xor(s, 16);  s  += __shfl_xor(s, 32);
    ss += __shfl_xor(ss, 16); ss += __shfl_xor(ss, 32);
    float mu = s * (1.f/128.f);
    float rstd = rsqrtf(ss * (1.f/128.f) - mu*mu + EPSL);
    #pragma unroll
    for (int ks = 0; ks < 4; ++ks) {
      union { unsigned u[4]; bf16x8 v8; } pk;
      #pragma unroll
      for (int p = 0; p < 4; ++p)
        pk.u[p] = cvtpk((v[ks][2*p]-mu)*rstd, (v[ks][2*p+1]-mu)*rstd);
      atok[t][ks] = pk.v8;
    }
  }

  // ---- MLP: 16 chunks of 32 hidden; no LDS, no barriers ----
  f32x4 O[8][2] = {};
  for (int j = 0; j < 16; ++j) {
    // fc1 swapped: S[T][t] : rows=h (hb+T*16), cols=tokens
    f32x4 S[2][2] = {{{0.f,0.f,0.f,0.f},{0.f,0.f,0.f,0.f}},
                     {{0.f,0.f,0.f,0.f},{0.f,0.f,0.f,0.f}}};
    #pragma unroll
    for (int ks = 0; ks < 4; ++ks) {
      bf16x8 w1f[2];
      #pragma unroll
      for (int T = 0; T < 2; ++T)
        w1f[T] = *(const bf16x8*)(W1t + (size_t)(j*32 + T*16 + i)*128 + ks*32 + fk);
      #pragma unroll
      for (int T = 0; T < 2; ++T)
        #pragma unroll
        for (int t = 0; t < 2; ++t)
          S[T][t] = __builtin_amdgcn_mfma_f32_16x16x32_bf16(w1f[T], atok[t][ks], S[T][t], 0, 0, 0);
    }
    // bias + gelu (tanh-form)
    float b1v[2][4];
    #pragma unroll
    for (int T = 0; T < 2; ++T)
      #pragma unroll
      for (int r = 0; r < 4; ++r)
        b1v[T][r] = b1p[j*32 + T*16 + gl*4 + r];
    #pragma unroll
    for (int T = 0; T < 2; ++T)
      #pragma unroll
      for (int t = 0; t < 2; ++t)
        #pragma unroll
        for (int r = 0; r < 4; ++r) {
          float vv = S[T][t][r] + b1v[T][r];
          float u = 1.5957691216057308f * vv * (1.f + 0.044715f*vv*vv);
          S[T][t][r] = vv / (1.f + __expf(-u));
        }
    // pack P to fc2 B-frag layout via cvt_pk + bpermute
    bf16x8 pf[2];
    #pragma unroll
    for (int t = 0; t < 2; ++t) {
      int A = (int)cvtpk(S[0][t][0], S[0][t][1]);
      int B = (int)cvtpk(S[0][t][2], S[0][t][3]);
      int C = (int)cvtpk(S[1][t][0], S[1][t][1]);
      int D = (int)cvtpk(S[1][t][2], S[1][t][3]);
      union { unsigned u[4]; bf16x8 v8; } pk;
      int a0 = __builtin_amdgcn_ds_bpermute(idx0, A);
      int c0 = __builtin_amdgcn_ds_bpermute(idx0, C);
      int b0 = __builtin_amdgcn_ds_bpermute(idx0, B);
      int d0 = __builtin_amdgcn_ds_bpermute(idx0, D);
      int a1 = __builtin_amdgcn_ds_bpermute(idx1, A);
      int c1 = __builtin_amdgcn_ds_bpermute(idx1, C);
      int b1r = __builtin_amdgcn_ds_bpermute(idx1, B);
      int d1 = __builtin_amdgcn_ds_bpermute(idx1, D);
      pk.u[0] = (unsigned)(hiHalf ? c0 : a0);
      pk.u[1] = (unsigned)(hiHalf ? d0 : b0);
      pk.u[2] = (unsigned)(hiHalf ? c1 : a1);
      pk.u[3] = (unsigned)(hiHalf ? d1 : b1r);
      pf[t] = pk.v8;
    }
    // fc2: O[jt][t] += W2frag(jt, k=j*32) x P
    #pragma unroll
    for (int jt = 0; jt < 8; ++jt) {
      bf16x8 w2f = *(const bf16x8*)(W2t + (size_t)(jt*16 + i)*512 + j*32 + fk);
      #pragma unroll
      for (int t = 0; t < 2; ++t)
        O[jt][t] = __builtin_amdgcn_mfma_f32_16x16x32_bf16(w2f, pf[t], O[jt][t], 0, 0, 0);
    }
  }

  // ---- epilogue: out[token][col] = xio + O + b2 ; C-layout: lane holds
  // token = l&15 (col axis), outcols jt*16 + gl*4 + r (row axis) ----
  #pragma unroll
  for (int t = 0; t < 2; ++t) {
    float* row = xio + (size_t)(tok0 + t*16 + i) * 128;
    #pragma unroll
    for (int jt = 0; jt < 8; ++jt) {
      int col = jt*16 + gl*4;
      float4 res = *(const float4*)(row + col);
      float4 bv = *(const float4*)(b2 + col);
      float4 o4;
      o4.x = res.x + O[jt][t][0] + bv.x;
      o4.y = res.y + O[jt][t][1] + bv.y;
      o4.z = res.z + O[jt][t][2] + bv.z;
      o4.w = res.w + O[jt][t][3] + bv.w;
      *(float4*)(row + col) = o4;
    }
  }
}

extern "C" void kernel_launch(void* const* d_in, const int* in_sizes, int n_in,
                              void* d_out, int out_size, void* d_ws, size_t ws_size,
                              hipStream_t stream)
{
  const float* x         = (const float*)d_in[0];
  const int*   rel_index = (const int*)  d_in[2];
  const float* n1g       = (const float*)d_in[3];
  const float* n1b       = (const float*)d_in[4];
  const float* qkv_w     = (const float*)d_in[5];
  const float* qkv_b     = (const float*)d_in[6];
  const float* rtab      = (const float*)d_in[7];
  const float* proj_w    = (const float*)d_in[8];
  const float* proj_b    = (const float*)d_in[9];
  const float* n2g       = (const float*)d_in[10];
  const float* n2b       = (const float*)d_in[11];
  const float* fc1_w     = (const float*)d_in[12];
  const float* fc1_b     = (const float*)d_in[13];
  const float* fc2_w     = (const float*)d_in[14];
  const float* fc2_b     = (const float*)d_in[15];
  float* out = (float*)d_out;

  unsigned short* buf0  = (unsigned short*)d_ws;          // ROWS*384
  unsigned short* buf1  = buf0 + (size_t)ROWS * 384;      // ROWS*128
  unsigned short* qkvT  = buf1 + (size_t)ROWS * 128;
  unsigned short* projT = qkvT + 384 * 128;
  unsigned short* fc1T  = projT + 128 * 128;
  unsigned short* fc2T  = fc1T + 512 * 128;
  float* biasC          = (float*)(fc2T + 128 * 512);     // 458752 f32
  float* b1p            = biasC + 458752;                 // 512 f32

  // 0. weights transpose/convert + bias fragments + folded fc1 bias
  k_prep_all<<<768, 256, 0, stream>>>(qkv_w, qkvT, proj_w, projT,
                                      fc1_w, fc1T, fc2_w, fc2T, n2g);
  k_prep_biasC<<<448, 256, 0, stream>>>(rel_index, rtab, biasC);
  k_prep_b1<<<2, 256, 0, stream>>>(fc1_b, n2b, fc1_w, b1p);

  // 1. fused LN1+shift+partition+qkv -> buf0
  k_qkv<<<ROWS/128, 256, 0, stream>>>(x, n1g, n1b, qkvT, qkv_b, buf0);

  // 2. MFMA windowed attention -> buf1
  k_attn_mfma<<<4096, 256, 0, stream>>>(buf0, biasC, buf1);

  // 3. proj + reverse/unshift scatter + residual -> out
  k_proj<<<ROWS/128, 256, 0, stream>>>(buf1, projT, proj_b, x, out);

  // 4. fused LN2 + fc1 + gelu + fc2 + residual -> out (no LDS, no barriers)
  k_mlp<<<ROWS/128, 256, 0, stream>>>(out, fc1T, b1p, fc2T, fc2_b);
}

// Round 10
// 246.997 us; speedup vs baseline: 1.2719x; 1.2719x over previous
//
#include <hip/hip_runtime.h>
#include <math.h>

#define ROWS 100352        // B * NW * N = 2*512*98
#define EPSL 1e-5f
#define SCALE_Q 0.17677669529663687f   // 32^-0.5

typedef __attribute__((ext_vector_type(8))) short bf16x8;
typedef __attribute__((ext_vector_type(4))) float f32x4;

__device__ __forceinline__ unsigned short f2b(float f) {
  union { float f; unsigned int u; } a; a.f = f;
  unsigned int u = a.u;
  return (unsigned short)((u + 0x7FFF + ((u >> 16) & 1)) >> 16);  // RNE
}

// partition-row -> x flat spatial index (applies shift)
__device__ __forceinline__ int map_row(int r) {
  int t = r;
  int tw = t % 7; t /= 7;
  int th = t % 7; t /= 7;
  int td = t & 1;  t >>= 1;
  int zw = t & 7;  t >>= 3;
  int zh = t & 7;  t >>= 3;
  int zd = t & 7;  int bb = t >> 3;
  int d = zd * 2 + td;
  int h = zh * 7 + th;
  int w = zw * 7 + tw;
  int sd = (d + 1) & 15;
  int sh = h + 3; if (sh >= 56) sh -= 56;
  int sw = w + 3; if (sw >= 56) sw -= 56;
  return ((bb * 16 + sd) * 56 + sh) * 56 + sw;
}

// weight transposes (W[K][N] -> Wt[N][K] bf16); SCALE folded into Q cols of qkvT;
// LN2 gamma folded into fc1T.
__global__ __launch_bounds__(256) void k_prep_all(
    const float* __restrict__ qkv_w, unsigned short* __restrict__ qkvT,
    const float* __restrict__ proj_w, unsigned short* __restrict__ projT,
    const float* __restrict__ fc1_w, unsigned short* __restrict__ fc1T,
    const float* __restrict__ fc2_w, unsigned short* __restrict__ fc2T,
    const float* __restrict__ n2g)
{
  int b = blockIdx.x, tid = threadIdx.x;
  if (b < 192) {                      // qkvT: [384][128]
    int id = b * 256 + tid;
    int n = id >> 7, k = id & 127;
    float v = qkv_w[(size_t)k * 384 + n];
    if (n < 128) v *= SCALE_Q;        // Q columns pre-scaled
    qkvT[id] = f2b(v);
  } else if (b < 256) {               // projT: [128][128]
    int id = (b - 192) * 256 + tid;
    int n = id >> 7, k = id & 127;
    projT[id] = f2b(proj_w[(size_t)k * 128 + n]);
  } else if (b < 512) {               // fc1T: [512][128], gamma folded
    int id = (b - 256) * 256 + tid;
    int n = id >> 7, k = id & 127;
    fc1T[id] = f2b(fc1_w[(size_t)k * 512 + n] * n2g[k]);
  } else {                            // fc2T: [128][512]
    int id = (b - 512) * 256 + tid;
    int n = id >> 9, k = id & 511;
    fc2T[id] = f2b(fc2_w[(size_t)k * 128 + n]);
  }
}

// b1p[h] = fc1_b[h] + sum_k n2b[k] * fc1_w[k][h]   (LN2 beta folded)
__global__ __launch_bounds__(256) void k_prep_b1(
    const float* __restrict__ fc1_b, const float* __restrict__ n2b,
    const float* __restrict__ fc1_w, float* __restrict__ b1p)
{
  int h = blockIdx.x * 256 + threadIdx.x;
  if (h >= 512) return;
  float acc = fc1_b[h];
  for (int k = 0; k < 128; ++k) acc += n2b[k] * fc1_w[(size_t)k * 512 + h];
  b1p[h] = acc;
}

// biasC[wm][h][rt][ct][lane][4] : rel-bias + shift-mask + pad, in MFMA C-frag layout.
__global__ __launch_bounds__(256) void k_prep_biasC(
    const int* __restrict__ relidx, const float* __restrict__ rtab,
    float* __restrict__ biasC)
{
  int id = blockIdx.x * 256 + threadIdx.x;   // 8*4*8*7*64 = 114688
  int l  = id & 63;  int t = id >> 6;
  int ct = t % 7;    t /= 7;
  int rt = t & 7;    t >>= 3;
  int h  = t & 3;    int wm = t >> 2;
  int n0 = rt*16 + ((l >> 4) << 2);
  int m  = ct*16 + (l & 15);
  float4 v;
  float* vp = &v.x;
  int cm = 0;
  if (m < 98)
    cm = (m >= 49 ? 1 : 0) | ((m % 49) >= 28 ? 2 : 0) | ((m % 7) >= 4 ? 4 : 0);
  #pragma unroll
  for (int r = 0; r < 4; ++r) {
    int n = n0 + r;
    float val;
    if (m >= 98) val = -10000.f;
    else if (n >= 98) val = 0.f;
    else {
      val = rtab[relidx[n*98 + m]*4 + h];
      int cn = (n >= 49 ? 1 : 0) | ((n % 49) >= 28 ? 2 : 0) | ((n % 7) >= 4 ? 4 : 0);
      if ((cn ^ cm) & wm) val -= 100.f;
    }
    vp[r] = val;
  }
  *(float4*)(biasC + (size_t)id*4) = v;
}

// ---- fused LN1 (+shift/partition gather) + qkv GEMM ----
__global__ __launch_bounds__(256) void k_qkv(
    const float* __restrict__ x, const float* __restrict__ g,
    const float* __restrict__ bta, const unsigned short* __restrict__ Wt,
    const float* __restrict__ bias, unsigned short* __restrict__ out)
{
  __shared__ unsigned short As[128 * 136];
  int tid = threadIdx.x;
  int row0 = blockIdx.x * 128;
  {
    int grp = tid >> 5, lane = tid & 31;
    float4 gv = *(const float4*)(g + lane*4);
    float4 bv = *(const float4*)(bta + lane*4);
    #pragma unroll
    for (int p = 0; p < 16; ++p) {
      int r = p * 8 + grp;
      size_t src = (size_t)map_row(row0 + r);
      float4 v = *(const float4*)(x + src * 128 + lane * 4);
      float s  = v.x + v.y + v.z + v.w;
      float ss = v.x*v.x + v.y*v.y + v.z*v.z + v.w*v.w;
      #pragma unroll
      for (int o = 16; o; o >>= 1) {
        s  += __shfl_xor(s,  o, 32);
        ss += __shfl_xor(ss, o, 32);
      }
      float mu   = s * (1.f/128.f);
      float rstd = rsqrtf(ss * (1.f/128.f) - mu*mu + EPSL);
      ushort4 o4;
      o4.x = f2b((v.x-mu)*rstd*gv.x + bv.x);
      o4.y = f2b((v.y-mu)*rstd*gv.y + bv.y);
      o4.z = f2b((v.z-mu)*rstd*gv.z + bv.z);
      o4.w = f2b((v.w-mu)*rstd*gv.w + bv.w);
      *(ushort4*)&As[r*136 + lane*4] = o4;
    }
  }
  __syncthreads();
  int l = tid & 63, w = tid >> 6;
  int wr = (w >> 1) * 64, wc = (w & 1) * 64;
  int fr = l & 15, gq = l >> 4, fk = gq * 8;
  for (int c = 0; c < 3; ++c) {
    int col0 = c * 128;
    float bmul = (c == 0) ? SCALE_Q : 1.f;   // Q bias pre-scaled to match weights
    f32x4 acc[4][4] = {};
    #pragma unroll
    for (int ks = 0; ks < 128; ks += 32) {
      bf16x8 af[4], bv[4];
      #pragma unroll
      for (int n = 0; n < 4; ++n)
        bv[n] = *(const bf16x8*)(Wt + (size_t)(col0 + wc + n*16 + fr)*128 + ks + fk);
      #pragma unroll
      for (int m = 0; m < 4; ++m)
        af[m] = *(bf16x8*)&As[(wr + m*16 + fr)*136 + ks + fk];
      #pragma unroll
      for (int m = 0; m < 4; ++m)
        #pragma unroll
        for (int n = 0; n < 4; ++n)
          acc[m][n] = __builtin_amdgcn_mfma_f32_16x16x32_bf16(af[m], bv[n], acc[m][n], 0, 0, 0);
    }
    #pragma unroll
    for (int m = 0; m < 4; ++m)
      #pragma unroll
      for (int r = 0; r < 4; ++r) {
        int grow = row0 + wr + m*16 + gq*4 + r;
        #pragma unroll
        for (int n = 0; n < 4; ++n) {
          int col = col0 + wc + n*16 + fr;
          out[(size_t)grow*384 + col] = f2b(acc[m][n][r] + bias[col]*bmul);
        }
      }
  }
}

// MFMA attention: bias/mask/scale baked into biasC (C-frag layout).
// XCD-swizzled blockIdx: the 4 heads of one window share qkv cache lines ->
// co-locate them (and 128 neighboring windows) on one XCD's L2.
__global__ __launch_bounds__(256, 4) void k_attn_mfma(
    const unsigned short* __restrict__ qkv,     // (ROWS, 384) bf16, Q pre-scaled
    const float* __restrict__ biasC,            // [8][4][8][7][64][4] f32
    unsigned short* __restrict__ o_part)        // (ROWS, 128) bf16
{
  __shared__ unsigned short Vt[32 * 136];   // [d][m]
  __shared__ unsigned short Pb[128 * 120];  // [n][m]
  int tid  = threadIdx.x;
  int bid  = blockIdx.x;
  int wg   = (bid & 7) * 512 + (bid >> 3);   // bijective: 4096 % 8 == 0
  int head = wg & 3;
  int win  = wg >> 2;
  int widx = win & 511;
  int wm = ((widx >> 6) == 7 ? 1 : 0) | (((widx >> 3) & 7) == 7 ? 2 : 0)
         | ((widx & 7) == 7 ? 4 : 0);
  const unsigned short* base = qkv + (size_t)win * 98 * 384 + head * 32;

  for (int it = tid; it < 32 * 128; it += 256) {
    int d = it & 31, m = it >> 5;
    unsigned short v = 0;
    if (m < 98) v = base[m*384 + 256 + d];
    Vt[d*136 + m] = v;
  }
  for (int it = tid; it < 128 * 8; it += 256) {
    int n = it >> 3, c2 = 112 + (it & 7);
    Pb[n*120 + c2] = 0;
  }

  int l = tid & 63, w = tid >> 6;
  int fr = l & 15, g = l >> 4, fk = g * 8;
  bf16x8 zero8 = {0,0,0,0,0,0,0,0};

  bf16x8 aq[2];
  #pragma unroll
  for (int lt = 0; lt < 2; ++lt) {
    int row = (w*2 + lt)*16 + fr;
    aq[lt] = (row < 98) ? *(const bf16x8*)(base + row*384 + fk) : zero8;
  }

  const float* bcb = biasC + (size_t)(wm*4 + head) * 8 * 7 * 256;
  f32x4 S[2][7];
  #pragma unroll
  for (int ct = 0; ct < 7; ++ct) {
    int m = ct*16 + fr;
    bf16x8 kb = (m < 98) ? *(const bf16x8*)(base + m*384 + 128 + fk) : zero8;
    #pragma unroll
    for (int lt = 0; lt < 2; ++lt) {
      f32x4 bc = *(const f32x4*)(bcb + ((w*2 + lt)*7 + ct)*256 + l*4);
      S[lt][ct] = __builtin_amdgcn_mfma_f32_16x16x32_bf16(aq[lt], kb, bc, 0, 0, 0);
    }
  }

  #pragma unroll
  for (int lt = 0; lt < 2; ++lt) {
    #pragma unroll
    for (int r = 0; r < 4; ++r) {
      float mx = S[lt][0][r];
      #pragma unroll
      for (int ct = 1; ct < 7; ++ct) mx = fmaxf(mx, S[lt][ct][r]);
      #pragma unroll
      for (int o = 8; o; o >>= 1) mx = fmaxf(mx, __shfl_xor(mx, o));
      float e[7], sum = 0.f;
      #pragma unroll
      for (int ct = 0; ct < 7; ++ct) { e[ct] = __expf(S[lt][ct][r] - mx); sum += e[ct]; }
      #pragma unroll
      for (int o = 8; o; o >>= 1) sum += __shfl_xor(sum, o);
      float inv = 1.f / sum;
      #pragma unroll
      for (int ct = 0; ct < 7; ++ct) S[lt][ct][r] = e[ct] * inv;
    }
  }

  #pragma unroll
  for (int lt = 0; lt < 2; ++lt)
    #pragma unroll
    for (int ct = 0; ct < 7; ++ct) {
      int m = ct*16 + fr;
      #pragma unroll
      for (int r = 0; r < 4; ++r) {
        int n = w*32 + lt*16 + g*4 + r;
        Pb[n*120 + m] = f2b(S[lt][ct][r]);
      }
    }
  __syncthreads();

  f32x4 O[2][2] = {};
  #pragma unroll
  for (int ks = 0; ks < 4; ++ks) {
    bf16x8 ap[2], bv[2];
    #pragma unroll
    for (int lt = 0; lt < 2; ++lt) {
      int rowoff = ((w*2 + lt)*16 + fr)*120;
      if (ks < 3) ap[lt] = *(bf16x8*)&Pb[rowoff + ks*32 + fk];
      else        ap[lt] = (g < 2) ? *(bf16x8*)&Pb[rowoff + 96 + fk] : zero8;
    }
    #pragma unroll
    for (int vt = 0; vt < 2; ++vt)
      bv[vt] = *(bf16x8*)&Vt[(vt*16 + fr)*136 + ks*32 + fk];
    #pragma unroll
    for (int lt = 0; lt < 2; ++lt)
      #pragma unroll
      for (int vt = 0; vt < 2; ++vt)
        O[lt][vt] = __builtin_amdgcn_mfma_f32_16x16x32_bf16(ap[lt], bv[vt], O[lt][vt], 0, 0, 0);
  }

  #pragma unroll
  for (int lt = 0; lt < 2; ++lt)
    #pragma unroll
    for (int r = 0; r < 4; ++r) {
      int n = w*32 + lt*16 + g*4 + r;
      if (n < 98) {
        unsigned short* orow = o_part + ((size_t)win*98 + n)*128 + head*32;
        #pragma unroll
        for (int vt = 0; vt < 2; ++vt)
          orow[vt*16 + fr] = f2b(O[lt][vt][r]);
      }
    }
}

// ---- proj GEMM + window-reverse/unshift scatter + residual ----
__global__ __launch_bounds__(256) void k_proj(
    const unsigned short* __restrict__ A,
    const unsigned short* __restrict__ Wt,
    const float* __restrict__ bias,
    const float* __restrict__ Xres, float* __restrict__ Cf)
{
  __shared__ unsigned short As[128 * 136];
  int tid = threadIdx.x;
  int row0 = blockIdx.x * 128;
  #pragma unroll
  for (int i = 0; i < 8; ++i) {
    int chunk = i * 256 + tid;
    int rr = chunk >> 4, off = (chunk & 15) * 8;
    *(uint4*)&As[rr*136 + off] = *(const uint4*)(A + (size_t)(row0+rr)*128 + off);
  }
  __syncthreads();
  int l = tid & 63, w = tid >> 6;
  int wr = (w >> 1) * 64, wc = (w & 1) * 64;
  int fr = l & 15, gq = l >> 4, fk = gq * 8;
  f32x4 acc[4][4] = {};
  #pragma unroll
  for (int ks = 0; ks < 128; ks += 32) {
    bf16x8 af[4], bv[4];
    #pragma unroll
    for (int n = 0; n < 4; ++n)
      bv[n] = *(const bf16x8*)(Wt + (size_t)(wc + n*16 + fr)*128 + ks + fk);
    #pragma unroll
    for (int m = 0; m < 4; ++m)
      af[m] = *(bf16x8*)&As[(wr + m*16 + fr)*136 + ks + fk];
    #pragma unroll
    for (int m = 0; m < 4; ++m)
      #pragma unroll
      for (int n = 0; n < 4; ++n)
        acc[m][n] = __builtin_amdgcn_mfma_f32_16x16x32_bf16(af[m], bv[n], acc[m][n], 0, 0, 0);
  }
  #pragma unroll
  for (int m = 0; m < 4; ++m)
    #pragma unroll
    for (int r = 0; r < 4; ++r) {
      int grow = row0 + wr + m*16 + gq*4 + r;
      size_t dst = (size_t)map_row(grow);
      #pragma unroll
      for (int n = 0; n < 4; ++n) {
        int col = wc + n*16 + fr;
        Cf[dst*128 + col] = acc[m][n][r] + bias[col] + Xres[dst*128 + col];
      }
    }
}

// ---- LN2 (pure normalize; gamma/beta folded into fc1T/b1p) -> bf16 ----
__global__ __launch_bounds__(256) void k_ln2(
    const float* __restrict__ x, unsigned short* __restrict__ out)
{
  int tid = threadIdx.x;
  int grp = tid >> 5, lane = tid & 31;
  size_t r = (size_t)blockIdx.x * 8 + grp;
  float4 v = *(const float4*)(x + r * 128 + lane * 4);
  float s  = v.x + v.y + v.z + v.w;
  float ss = v.x*v.x + v.y*v.y + v.z*v.z + v.w*v.w;
  #pragma unroll
  for (int o = 16; o; o >>= 1) {
    s  += __shfl_xor(s,  o, 32);
    ss += __shfl_xor(ss, o, 32);
  }
  float mu   = s * (1.f/128.f);
  float rstd = rsqrtf(ss * (1.f/128.f) - mu*mu + EPSL);
  ushort4 o4;
  o4.x = f2b((v.x-mu)*rstd);
  o4.y = f2b((v.y-mu)*rstd);
  o4.z = f2b((v.z-mu)*rstd);
  o4.w = f2b((v.w-mu)*rstd);
  *(ushort4*)(out + r*128 + lane*4) = o4;
}

// ---- fc1 + gelu + fc2 + residual (round-8 loop, LN removed) ----
// 128-row tile, 512 threads (8 waves, 4m x 2n frags/wave). A staged bf16.
__global__ __launch_bounds__(512, 4) void k_mlp(
    float* __restrict__ xio,
    const unsigned short* __restrict__ h2,    // (ROWS,128) bf16, normalized
    const unsigned short* __restrict__ W1t,   // [512][128], gamma folded
    const float* __restrict__ b1p,            // [512], beta folded
    const unsigned short* __restrict__ W2t,   // [128][512]
    const float* __restrict__ b2)
{
  __shared__ unsigned short As[128 * 136];
  __shared__ unsigned short Pb[128 * 136];
  int tid = threadIdx.x;
  int row0 = blockIdx.x * 128;
  // stage A (bf16, coalesced): 128x128 shorts in 4 passes of 512 x uint4
  #pragma unroll
  for (int i = 0; i < 4; ++i) {
    int chunk = i * 512 + tid;
    int rr = chunk >> 4, off = (chunk & 15) * 8;
    *(uint4*)&As[rr*136 + off] = *(const uint4*)(h2 + (size_t)(row0+rr)*128 + off);
  }
  __syncthreads();
  int l = tid & 63, w = tid >> 6;          // w 0..7
  int wr = (w & 1) * 64, wc = (w >> 1) * 32;
  int fr = l & 15, gq = l >> 4, fk = gq * 8;

  f32x4 O[4][2] = {};
  for (int j = 0; j < 4; ++j) {
    // fc1 chunk: S = A @ W1t[j*128 .. +128]^T
    f32x4 S[4][2] = {};
    #pragma unroll
    for (int ks = 0; ks < 4; ++ks) {
      bf16x8 af[4], bv[2];
      #pragma unroll
      for (int n = 0; n < 2; ++n)
        bv[n] = *(const bf16x8*)(W1t + (size_t)(j*128 + wc + n*16 + fr)*128 + ks*32 + fk);
      #pragma unroll
      for (int m = 0; m < 4; ++m)
        af[m] = *(bf16x8*)&As[(wr + m*16 + fr)*136 + ks*32 + fk];
      #pragma unroll
      for (int m = 0; m < 4; ++m)
        #pragma unroll
        for (int n = 0; n < 2; ++n)
          S[m][n] = __builtin_amdgcn_mfma_f32_16x16x32_bf16(af[m], bv[n], S[m][n], 0, 0, 0);
    }
    // bias + gelu -> Pb
    #pragma unroll
    for (int m = 0; m < 4; ++m)
      #pragma unroll
      for (int n = 0; n < 2; ++n) {
        int col = wc + n*16 + fr;
        float bb = b1p[j*128 + col];
        #pragma unroll
        for (int r = 0; r < 4; ++r) {
          float v = S[m][n][r] + bb;
          float u = 1.5957691216057308f * v * (1.f + 0.044715f*v*v);
          v = v / (1.f + __expf(-u));
          Pb[(wr + m*16 + gq*4 + r)*136 + col] = f2b(v);
        }
      }
    __syncthreads();
    // fc2 chunk: O += P @ W2t[:, j*128 .. +128]^T
    #pragma unroll
    for (int ks = 0; ks < 4; ++ks) {
      bf16x8 ap[4], bv[2];
      #pragma unroll
      for (int n = 0; n < 2; ++n)
        bv[n] = *(const bf16x8*)(W2t + (size_t)(wc + n*16 + fr)*512 + j*128 + ks*32 + fk);
      #pragma unroll
      for (int m = 0; m < 4; ++m)
        ap[m] = *(bf16x8*)&Pb[(wr + m*16 + fr)*136 + ks*32 + fk];
      #pragma unroll
      for (int m = 0; m < 4; ++m)
        #pragma unroll
        for (int n = 0; n < 2; ++n)
          O[m][n] = __builtin_amdgcn_mfma_f32_16x16x32_bf16(ap[m], bv[n], O[m][n], 0, 0, 0);
    }
    __syncthreads();
  }
  #pragma unroll
  for (int m = 0; m < 4; ++m)
    #pragma unroll
    for (int r = 0; r < 4; ++r) {
      size_t grow = row0 + wr + m*16 + gq*4 + r;
      #pragma unroll
      for (int n = 0; n < 2; ++n) {
        int col = wc + n*16 + fr;
        xio[grow*128 + col] += O[m][n][r] + b2[col];
      }
    }
}

extern "C" void kernel_launch(void* const* d_in, const int* in_sizes, int n_in,
                              void* d_out, int out_size, void* d_ws, size_t ws_size,
                              hipStream_t stream)
{
  const float* x         = (const float*)d_in[0];
  const int*   rel_index = (const int*)  d_in[2];
  const float* n1g       = (const float*)d_in[3];
  const float* n1b       = (const float*)d_in[4];
  const float* qkv_w     = (const float*)d_in[5];
  const float* qkv_b     = (const float*)d_in[6];
  const float* rtab      = (const float*)d_in[7];
  const float* proj_w    = (const float*)d_in[8];
  const float* proj_b    = (const float*)d_in[9];
  const float* n2g       = (const float*)d_in[10];
  const float* n2b       = (const float*)d_in[11];
  const float* fc1_w     = (const float*)d_in[12];
  const float* fc1_b     = (const float*)d_in[13];
  const float* fc2_w     = (const float*)d_in[14];
  const float* fc2_b     = (const float*)d_in[15];
  float* out = (float*)d_out;

  unsigned short* buf0  = (unsigned short*)d_ws;          // ROWS*384 (qkv, later h2)
  unsigned short* buf1  = buf0 + (size_t)ROWS * 384;      // ROWS*128
  unsigned short* qkvT  = buf1 + (size_t)ROWS * 128;
  unsigned short* projT = qkvT + 384 * 128;
  unsigned short* fc1T  = projT + 128 * 128;
  unsigned short* fc2T  = fc1T + 512 * 128;
  float* biasC          = (float*)(fc2T + 128 * 512);     // 458752 f32
  float* b1p            = biasC + 458752;                 // 512 f32

  // 0. weights transpose/convert + bias fragments + folded fc1 bias
  k_prep_all<<<768, 256, 0, stream>>>(qkv_w, qkvT, proj_w, projT,
                                      fc1_w, fc1T, fc2_w, fc2T, n2g);
  k_prep_biasC<<<448, 256, 0, stream>>>(rel_index, rtab, biasC);
  k_prep_b1<<<2, 256, 0, stream>>>(fc1_b, n2b, fc1_w, b1p);

  // 1. fused LN1+shift+partition+qkv -> buf0
  k_qkv<<<ROWS/128, 256, 0, stream>>>(x, n1g, n1b, qkvT, qkv_b, buf0);

  // 2. MFMA windowed attention (XCD-swizzled) -> buf1
  k_attn_mfma<<<4096, 256, 0, stream>>>(buf0, biasC, buf1);

  // 3. proj + reverse/unshift scatter + residual -> out
  k_proj<<<ROWS/128, 256, 0, stream>>>(buf1, projT, proj_b, x, out);

  // 4. LN2 -> h2 (bf16, reuse buf0; qkv no longer needed)
  k_ln2<<<ROWS/8, 256, 0, stream>>>(out, buf0);

  // 5. fc1 + gelu + fc2 + residual -> out
  k_mlp<<<ROWS/128, 512, 0, stream>>>(out, buf0, fc1T, b1p, fc2T, fc2_b);
}

// Round 11
// 234.609 us; speedup vs baseline: 1.3391x; 1.0528x over previous
//
#include <hip/hip_runtime.h>
#include <math.h>

#define ROWS 100352        // B * NW * N = 2*512*98
#define EPSL 1e-5f
#define SCALE_Q 0.17677669529663687f   // 32^-0.5

typedef __attribute__((ext_vector_type(8))) short bf16x8;
typedef __attribute__((ext_vector_type(4))) float f32x4;

__device__ __forceinline__ unsigned short f2b(float f) {
  union { float f; unsigned int u; } a; a.f = f;
  unsigned int u = a.u;
  return (unsigned short)((u + 0x7FFF + ((u >> 16) & 1)) >> 16);  // RNE
}

// partition-row -> x flat spatial index (applies shift)
__device__ __forceinline__ int map_row(int r) {
  int t = r;
  int tw = t % 7; t /= 7;
  int th = t % 7; t /= 7;
  int td = t & 1;  t >>= 1;
  int zw = t & 7;  t >>= 3;
  int zh = t & 7;  t >>= 3;
  int zd = t & 7;  int bb = t >> 3;
  int d = zd * 2 + td;
  int h = zh * 7 + th;
  int w = zw * 7 + tw;
  int sd = (d + 1) & 15;
  int sh = h + 3; if (sh >= 56) sh -= 56;
  int sw = w + 3; if (sw >= 56) sw -= 56;
  return ((bb * 16 + sd) * 56 + sh) * 56 + sw;
}

// weight transposes (W[K][N] -> Wt[N][K] bf16); SCALE folded into Q cols of qkvT;
// LN2 gamma folded into fc1T.
__global__ __launch_bounds__(256) void k_prep_all(
    const float* __restrict__ qkv_w, unsigned short* __restrict__ qkvT,
    const float* __restrict__ proj_w, unsigned short* __restrict__ projT,
    const float* __restrict__ fc1_w, unsigned short* __restrict__ fc1T,
    const float* __restrict__ fc2_w, unsigned short* __restrict__ fc2T,
    const float* __restrict__ n2g)
{
  int b = blockIdx.x, tid = threadIdx.x;
  if (b < 192) {                      // qkvT: [384][128]
    int id = b * 256 + tid;
    int n = id >> 7, k = id & 127;
    float v = qkv_w[(size_t)k * 384 + n];
    if (n < 128) v *= SCALE_Q;        // Q columns pre-scaled
    qkvT[id] = f2b(v);
  } else if (b < 256) {               // projT: [128][128]
    int id = (b - 192) * 256 + tid;
    int n = id >> 7, k = id & 127;
    projT[id] = f2b(proj_w[(size_t)k * 128 + n]);
  } else if (b < 512) {               // fc1T: [512][128], gamma folded
    int id = (b - 256) * 256 + tid;
    int n = id >> 7, k = id & 127;
    fc1T[id] = f2b(fc1_w[(size_t)k * 512 + n] * n2g[k]);
  } else {                            // fc2T: [128][512]
    int id = (b - 512) * 256 + tid;
    int n = id >> 9, k = id & 511;
    fc2T[id] = f2b(fc2_w[(size_t)k * 128 + n]);
  }
}

// b1p[h] = fc1_b[h] + sum_k n2b[k] * fc1_w[k][h]   (LN2 beta folded)
__global__ __launch_bounds__(256) void k_prep_b1(
    const float* __restrict__ fc1_b, const float* __restrict__ n2b,
    const float* __restrict__ fc1_w, float* __restrict__ b1p)
{
  int h = blockIdx.x * 256 + threadIdx.x;
  if (h >= 512) return;
  float acc = fc1_b[h];
  for (int k = 0; k < 128; ++k) acc += n2b[k] * fc1_w[(size_t)k * 512 + h];
  b1p[h] = acc;
}

// biasC[wm][h][rt][ct][lane][4] : rel-bias + shift-mask + pad, in MFMA C-frag layout.
__global__ __launch_bounds__(256) void k_prep_biasC(
    const int* __restrict__ relidx, const float* __restrict__ rtab,
    float* __restrict__ biasC)
{
  int id = blockIdx.x * 256 + threadIdx.x;   // 8*4*8*7*64 = 114688
  int l  = id & 63;  int t = id >> 6;
  int ct = t % 7;    t /= 7;
  int rt = t & 7;    t >>= 3;
  int h  = t & 3;    int wm = t >> 2;
  int n0 = rt*16 + ((l >> 4) << 2);
  int m  = ct*16 + (l & 15);
  float4 v;
  float* vp = &v.x;
  int cm = 0;
  if (m < 98)
    cm = (m >= 49 ? 1 : 0) | ((m % 49) >= 28 ? 2 : 0) | ((m % 7) >= 4 ? 4 : 0);
  #pragma unroll
  for (int r = 0; r < 4; ++r) {
    int n = n0 + r;
    float val;
    if (m >= 98) val = -10000.f;
    else if (n >= 98) val = 0.f;
    else {
      val = rtab[relidx[n*98 + m]*4 + h];
      int cn = (n >= 49 ? 1 : 0) | ((n % 49) >= 28 ? 2 : 0) | ((n % 7) >= 4 ? 4 : 0);
      if ((cn ^ cm) & wm) val -= 100.f;
    }
    vp[r] = val;
  }
  *(float4*)(biasC + (size_t)id*4) = v;
}

// ---- fused LN1 (+shift/partition gather) + qkv GEMM ----
__global__ __launch_bounds__(256) void k_qkv(
    const float* __restrict__ x, const float* __restrict__ g,
    const float* __restrict__ bta, const unsigned short* __restrict__ Wt,
    const float* __restrict__ bias, unsigned short* __restrict__ out)
{
  __shared__ unsigned short As[128 * 136];
  int tid = threadIdx.x;
  int row0 = blockIdx.x * 128;
  {
    int grp = tid >> 5, lane = tid & 31;
    float4 gv = *(const float4*)(g + lane*4);
    float4 bv = *(const float4*)(bta + lane*4);
    #pragma unroll
    for (int p = 0; p < 16; ++p) {
      int r = p * 8 + grp;
      size_t src = (size_t)map_row(row0 + r);
      float4 v = *(const float4*)(x + src * 128 + lane * 4);
      float s  = v.x + v.y + v.z + v.w;
      float ss = v.x*v.x + v.y*v.y + v.z*v.z + v.w*v.w;
      #pragma unroll
      for (int o = 16; o; o >>= 1) {
        s  += __shfl_xor(s,  o, 32);
        ss += __shfl_xor(ss, o, 32);
      }
      float mu   = s * (1.f/128.f);
      float rstd = rsqrtf(ss * (1.f/128.f) - mu*mu + EPSL);
      ushort4 o4;
      o4.x = f2b((v.x-mu)*rstd*gv.x + bv.x);
      o4.y = f2b((v.y-mu)*rstd*gv.y + bv.y);
      o4.z = f2b((v.z-mu)*rstd*gv.z + bv.z);
      o4.w = f2b((v.w-mu)*rstd*gv.w + bv.w);
      *(ushort4*)&As[r*136 + lane*4] = o4;
    }
  }
  __syncthreads();
  int l = tid & 63, w = tid >> 6;
  int wr = (w >> 1) * 64, wc = (w & 1) * 64;
  int fr = l & 15, gq = l >> 4, fk = gq * 8;
  for (int c = 0; c < 3; ++c) {
    int col0 = c * 128;
    float bmul = (c == 0) ? SCALE_Q : 1.f;   // Q bias pre-scaled to match weights
    f32x4 acc[4][4] = {};
    #pragma unroll
    for (int ks = 0; ks < 128; ks += 32) {
      bf16x8 af[4], bv[4];
      #pragma unroll
      for (int n = 0; n < 4; ++n)
        bv[n] = *(const bf16x8*)(Wt + (size_t)(col0 + wc + n*16 + fr)*128 + ks + fk);
      #pragma unroll
      for (int m = 0; m < 4; ++m)
        af[m] = *(bf16x8*)&As[(wr + m*16 + fr)*136 + ks + fk];
      #pragma unroll
      for (int m = 0; m < 4; ++m)
        #pragma unroll
        for (int n = 0; n < 4; ++n)
          acc[m][n] = __builtin_amdgcn_mfma_f32_16x16x32_bf16(af[m], bv[n], acc[m][n], 0, 0, 0);
    }
    #pragma unroll
    for (int m = 0; m < 4; ++m)
      #pragma unroll
      for (int r = 0; r < 4; ++r) {
        int grow = row0 + wr + m*16 + gq*4 + r;
        #pragma unroll
        for (int n = 0; n < 4; ++n) {
          int col = col0 + wc + n*16 + fr;
          out[(size_t)grow*384 + col] = f2b(acc[m][n][r] + bias[col]*bmul);
        }
      }
  }
}

// MFMA attention: bias/mask/scale baked into biasC (C-frag layout). XCD-swizzled.
__global__ __launch_bounds__(256, 4) void k_attn_mfma(
    const unsigned short* __restrict__ qkv,     // (ROWS, 384) bf16, Q pre-scaled
    const float* __restrict__ biasC,            // [8][4][8][7][64][4] f32
    unsigned short* __restrict__ o_part)        // (ROWS, 128) bf16
{
  __shared__ unsigned short Vt[32 * 136];   // [d][m]
  __shared__ unsigned short Pb[128 * 120];  // [n][m]
  int tid  = threadIdx.x;
  int bid  = blockIdx.x;
  int wg   = (bid & 7) * 512 + (bid >> 3);   // bijective: 4096 % 8 == 0
  int head = wg & 3;
  int win  = wg >> 2;
  int widx = win & 511;
  int wm = ((widx >> 6) == 7 ? 1 : 0) | (((widx >> 3) & 7) == 7 ? 2 : 0)
         | ((widx & 7) == 7 ? 4 : 0);
  const unsigned short* base = qkv + (size_t)win * 98 * 384 + head * 32;

  for (int it = tid; it < 32 * 128; it += 256) {
    int d = it & 31, m = it >> 5;
    unsigned short v = 0;
    if (m < 98) v = base[m*384 + 256 + d];
    Vt[d*136 + m] = v;
  }
  for (int it = tid; it < 128 * 8; it += 256) {
    int n = it >> 3, c2 = 112 + (it & 7);
    Pb[n*120 + c2] = 0;
  }

  int l = tid & 63, w = tid >> 6;
  int fr = l & 15, g = l >> 4, fk = g * 8;
  bf16x8 zero8 = {0,0,0,0,0,0,0,0};

  bf16x8 aq[2];
  #pragma unroll
  for (int lt = 0; lt < 2; ++lt) {
    int row = (w*2 + lt)*16 + fr;
    aq[lt] = (row < 98) ? *(const bf16x8*)(base + row*384 + fk) : zero8;
  }

  const float* bcb = biasC + (size_t)(wm*4 + head) * 8 * 7 * 256;
  f32x4 S[2][7];
  #pragma unroll
  for (int ct = 0; ct < 7; ++ct) {
    int m = ct*16 + fr;
    bf16x8 kb = (m < 98) ? *(const bf16x8*)(base + m*384 + 128 + fk) : zero8;
    #pragma unroll
    for (int lt = 0; lt < 2; ++lt) {
      f32x4 bc = *(const f32x4*)(bcb + ((w*2 + lt)*7 + ct)*256 + l*4);
      S[lt][ct] = __builtin_amdgcn_mfma_f32_16x16x32_bf16(aq[lt], kb, bc, 0, 0, 0);
    }
  }

  #pragma unroll
  for (int lt = 0; lt < 2; ++lt) {
    #pragma unroll
    for (int r = 0; r < 4; ++r) {
      float mx = S[lt][0][r];
      #pragma unroll
      for (int ct = 1; ct < 7; ++ct) mx = fmaxf(mx, S[lt][ct][r]);
      #pragma unroll
      for (int o = 8; o; o >>= 1) mx = fmaxf(mx, __shfl_xor(mx, o));
      float e[7], sum = 0.f;
      #pragma unroll
      for (int ct = 0; ct < 7; ++ct) { e[ct] = __expf(S[lt][ct][r] - mx); sum += e[ct]; }
      #pragma unroll
      for (int o = 8; o; o >>= 1) sum += __shfl_xor(sum, o);
      float inv = 1.f / sum;
      #pragma unroll
      for (int ct = 0; ct < 7; ++ct) S[lt][ct][r] = e[ct] * inv;
    }
  }

  #pragma unroll
  for (int lt = 0; lt < 2; ++lt)
    #pragma unroll
    for (int ct = 0; ct < 7; ++ct) {
      int m = ct*16 + fr;
      #pragma unroll
      for (int r = 0; r < 4; ++r) {
        int n = w*32 + lt*16 + g*4 + r;
        Pb[n*120 + m] = f2b(S[lt][ct][r]);
      }
    }
  __syncthreads();

  f32x4 O[2][2] = {};
  #pragma unroll
  for (int ks = 0; ks < 4; ++ks) {
    bf16x8 ap[2], bv[2];
    #pragma unroll
    for (int lt = 0; lt < 2; ++lt) {
      int rowoff = ((w*2 + lt)*16 + fr)*120;
      if (ks < 3) ap[lt] = *(bf16x8*)&Pb[rowoff + ks*32 + fk];
      else        ap[lt] = (g < 2) ? *(bf16x8*)&Pb[rowoff + 96 + fk] : zero8;
    }
    #pragma unroll
    for (int vt = 0; vt < 2; ++vt)
      bv[vt] = *(bf16x8*)&Vt[(vt*16 + fr)*136 + ks*32 + fk];
    #pragma unroll
    for (int lt = 0; lt < 2; ++lt)
      #pragma unroll
      for (int vt = 0; vt < 2; ++vt)
        O[lt][vt] = __builtin_amdgcn_mfma_f32_16x16x32_bf16(ap[lt], bv[vt], O[lt][vt], 0, 0, 0);
  }

  #pragma unroll
  for (int lt = 0; lt < 2; ++lt)
    #pragma unroll
    for (int r = 0; r < 4; ++r) {
      int n = w*32 + lt*16 + g*4 + r;
      if (n < 98) {
        unsigned short* orow = o_part + ((size_t)win*98 + n)*128 + head*32;
        #pragma unroll
        for (int vt = 0; vt < 2; ++vt)
          orow[vt*16 + fr] = f2b(O[lt][vt][r]);
      }
    }
}

// ---- proj GEMM + scatter + residual + fused LN2 (h2 bf16 out) ----
__global__ __launch_bounds__(256) void k_proj(
    const unsigned short* __restrict__ A,
    const unsigned short* __restrict__ Wt,
    const float* __restrict__ bias,
    const float* __restrict__ Xres, float* __restrict__ Cf,
    unsigned short* __restrict__ h2out)
{
  __shared__ unsigned short As[128 * 136];
  __shared__ float red[128][2][2];
  int tid = threadIdx.x;
  int row0 = blockIdx.x * 128;
  #pragma unroll
  for (int i = 0; i < 8; ++i) {
    int chunk = i * 256 + tid;
    int rr = chunk >> 4, off = (chunk & 15) * 8;
    *(uint4*)&As[rr*136 + off] = *(const uint4*)(A + (size_t)(row0+rr)*128 + off);
  }
  __syncthreads();
  int l = tid & 63, w = tid >> 6;
  int wr = (w >> 1) * 64, wc = (w & 1) * 64;
  int fr = l & 15, gq = l >> 4, fk = gq * 8;
  f32x4 acc[4][4] = {};
  #pragma unroll
  for (int ks = 0; ks < 128; ks += 32) {
    bf16x8 af[4], bv[4];
    #pragma unroll
    for (int n = 0; n < 4; ++n)
      bv[n] = *(const bf16x8*)(Wt + (size_t)(wc + n*16 + fr)*128 + ks + fk);
    #pragma unroll
    for (int m = 0; m < 4; ++m)
      af[m] = *(bf16x8*)&As[(wr + m*16 + fr)*136 + ks + fk];
    #pragma unroll
    for (int m = 0; m < 4; ++m)
      #pragma unroll
      for (int n = 0; n < 4; ++n)
        acc[m][n] = __builtin_amdgcn_mfma_f32_16x16x32_bf16(af[m], bv[n], acc[m][n], 0, 0, 0);
  }
  // t = acc + bias + x[dst] (in place) ; per-row LN partials
  int dst[4][4];
  #pragma unroll
  for (int m = 0; m < 4; ++m)
    #pragma unroll
    for (int r = 0; r < 4; ++r)
      dst[m][r] = map_row(row0 + wr + m*16 + gq*4 + r);
  #pragma unroll
  for (int m = 0; m < 4; ++m)
    #pragma unroll
    for (int n = 0; n < 4; ++n) {
      int col = wc + n*16 + fr;
      float bb = bias[col];
      #pragma unroll
      for (int r = 0; r < 4; ++r)
        acc[m][n][r] += bb + Xres[(size_t)dst[m][r]*128 + col];
    }
  #pragma unroll
  for (int m = 0; m < 4; ++m)
    #pragma unroll
    for (int r = 0; r < 4; ++r) {
      float s  = acc[m][0][r] + acc[m][1][r] + acc[m][2][r] + acc[m][3][r];
      float ss = acc[m][0][r]*acc[m][0][r] + acc[m][1][r]*acc[m][1][r]
               + acc[m][2][r]*acc[m][2][r] + acc[m][3][r]*acc[m][3][r];
      #pragma unroll
      for (int o = 8; o; o >>= 1) {
        s  += __shfl_xor(s,  o);
        ss += __shfl_xor(ss, o);
      }
      if (fr == 0) {
        int R = wr + m*16 + gq*4 + r;
        red[R][w & 1][0] = s;
        red[R][w & 1][1] = ss;
      }
    }
  __syncthreads();
  #pragma unroll
  for (int m = 0; m < 4; ++m)
    #pragma unroll
    for (int r = 0; r < 4; ++r) {
      int R = wr + m*16 + gq*4 + r;
      float sum  = red[R][0][0] + red[R][1][0];
      float ssum = red[R][0][1] + red[R][1][1];
      float mu   = sum * (1.f/128.f);
      float rstd = rsqrtf(ssum * (1.f/128.f) - mu*mu + EPSL);
      size_t db = (size_t)dst[m][r] * 128;
      #pragma unroll
      for (int n = 0; n < 4; ++n) {
        int col = wc + n*16 + fr;
        float t = acc[m][n][r];
        Cf[db + col] = t;
        h2out[db + col] = f2b((t - mu) * rstd);
      }
    }
}

// ---- fc1 + gelu + fc2 + residual ; software-pipelined 64-wide hidden chunks ----
// 512 threads (8 waves = 2 row x 4 col), double-buffered Pb, ONE barrier/chunk:
// iteration j issues fc1(j+1)->Pb[b^1] first, then fc2(j) from Pb[b].
__global__ __launch_bounds__(512, 4) void k_mlp(
    float* __restrict__ xio,
    const unsigned short* __restrict__ h2,    // (ROWS,128) bf16, normalized
    const unsigned short* __restrict__ W1t,   // [512][128], gamma folded
    const float* __restrict__ b1p,            // [512], beta folded
    const unsigned short* __restrict__ W2t,   // [128][512]
    const float* __restrict__ b2)
{
  __shared__ unsigned short As[128 * 136];
  __shared__ unsigned short Pb[2][128 * 72];
  int tid = threadIdx.x;
  int row0 = blockIdx.x * 128;
  #pragma unroll
  for (int i = 0; i < 4; ++i) {
    int chunk = i * 512 + tid;
    int rr = chunk >> 4, off = (chunk & 15) * 8;
    *(uint4*)&As[rr*136 + off] = *(const uint4*)(h2 + (size_t)(row0+rr)*128 + off);
  }
  __syncthreads();
  int l = tid & 63, w = tid >> 6;          // w 0..7
  int wr = (w & 1) * 64, cw = w >> 1;      // 2 row-waves x 4 col-waves
  int fr = l & 15, gq = l >> 4, fk = gq * 8;
  int hl = cw * 16 + fr;                   // hidden lane within 64-chunk

  f32x4 O[4][2] = {};

  auto fc1 = [&](int jj, unsigned short* pw) {
    f32x4 S[4] = {};
    #pragma unroll
    for (int ks = 0; ks < 4; ++ks) {
      bf16x8 bv = *(const bf16x8*)(W1t + (size_t)(jj*64 + hl)*128 + ks*32 + fk);
      #pragma unroll
      for (int m = 0; m < 4; ++m) {
        bf16x8 af = *(bf16x8*)&As[(wr + m*16 + fr)*136 + ks*32 + fk];
        S[m] = __builtin_amdgcn_mfma_f32_16x16x32_bf16(af, bv, S[m], 0, 0, 0);
      }
    }
    float bb = b1p[jj*64 + hl];
    #pragma unroll
    for (int m = 0; m < 4; ++m)
      #pragma unroll
      for (int r = 0; r < 4; ++r) {
        float v = S[m][r] + bb;
        float u = 1.5957691216057308f * v * (1.f + 0.044715f*v*v);
        v = v / (1.f + __expf(-u));
        pw[(wr + m*16 + gq*4 + r)*72 + hl] = f2b(v);
      }
  };

  fc1(0, Pb[0]);
  __syncthreads();
  for (int j = 0; j < 8; ++j) {
    if (j < 7) fc1(j + 1, Pb[(j + 1) & 1]);   // issue next chunk first
    const unsigned short* pb = Pb[j & 1];
    #pragma unroll
    for (int ks = 0; ks < 2; ++ks) {
      bf16x8 ap[4], bv[2];
      #pragma unroll
      for (int n = 0; n < 2; ++n)
        bv[n] = *(const bf16x8*)(W2t + (size_t)(cw*32 + n*16 + fr)*512 + j*64 + ks*32 + fk);
      #pragma unroll
      for (int m = 0; m < 4; ++m)
        ap[m] = *(const bf16x8*)&pb[(wr + m*16 + fr)*72 + ks*32 + fk];
      #pragma unroll
      for (int m = 0; m < 4; ++m)
        #pragma unroll
        for (int n = 0; n < 2; ++n)
          O[m][n] = __builtin_amdgcn_mfma_f32_16x16x32_bf16(ap[m], bv[n], O[m][n], 0, 0, 0);
    }
    __syncthreads();
  }
  #pragma unroll
  for (int m = 0; m < 4; ++m)
    #pragma unroll
    for (int r = 0; r < 4; ++r) {
      size_t grow = row0 + wr + m*16 + gq*4 + r;
      #pragma unroll
      for (int n = 0; n < 2; ++n) {
        int col = cw*32 + n*16 + fr;
        xio[grow*128 + col] += O[m][n][r] + b2[col];
      }
    }
}

extern "C" void kernel_launch(void* const* d_in, const int* in_sizes, int n_in,
                              void* d_out, int out_size, void* d_ws, size_t ws_size,
                              hipStream_t stream)
{
  const float* x         = (const float*)d_in[0];
  const int*   rel_index = (const int*)  d_in[2];
  const float* n1g       = (const float*)d_in[3];
  const float* n1b       = (const float*)d_in[4];
  const float* qkv_w     = (const float*)d_in[5];
  const float* qkv_b     = (const float*)d_in[6];
  const float* rtab      = (const float*)d_in[7];
  const float* proj_w    = (const float*)d_in[8];
  const float* proj_b    = (const float*)d_in[9];
  const float* n2g       = (const float*)d_in[10];
  const float* n2b       = (const float*)d_in[11];
  const float* fc1_w     = (const float*)d_in[12];
  const float* fc1_b     = (const float*)d_in[13];
  const float* fc2_w     = (const float*)d_in[14];
  const float* fc2_b     = (const float*)d_in[15];
  float* out = (float*)d_out;

  unsigned short* buf0  = (unsigned short*)d_ws;          // ROWS*384 (qkv, later h2)
  unsigned short* buf1  = buf0 + (size_t)ROWS * 384;      // ROWS*128
  unsigned short* qkvT  = buf1 + (size_t)ROWS * 128;
  unsigned short* projT = qkvT + 384 * 128;
  unsigned short* fc1T  = projT + 128 * 128;
  unsigned short* fc2T  = fc1T + 512 * 128;
  float* biasC          = (float*)(fc2T + 128 * 512);     // 458752 f32
  float* b1p            = biasC + 458752;                 // 512 f32

  // 0. weights transpose/convert + bias fragments + folded fc1 bias
  k_prep_all<<<768, 256, 0, stream>>>(qkv_w, qkvT, proj_w, projT,
                                      fc1_w, fc1T, fc2_w, fc2T, n2g);
  k_prep_biasC<<<448, 256, 0, stream>>>(rel_index, rtab, biasC);
  k_prep_b1<<<2, 256, 0, stream>>>(fc1_b, n2b, fc1_w, b1p);

  // 1. fused LN1+shift+partition+qkv -> buf0
  k_qkv<<<ROWS/128, 256, 0, stream>>>(x, n1g, n1b, qkvT, qkv_b, buf0);

  // 2. MFMA windowed attention (XCD-swizzled) -> buf1
  k_attn_mfma<<<4096, 256, 0, stream>>>(buf0, biasC, buf1);

  // 3. proj + scatter + residual + LN2 -> out (fp32) + buf0 (h2 bf16)
  k_proj<<<ROWS/128, 256, 0, stream>>>(buf1, projT, proj_b, x, out, buf0);

  // 4. pipelined fc1 + gelu + fc2 + residual -> out
  k_mlp<<<ROWS/128, 512, 0, stream>>>(out, buf0, fc1T, b1p, fc2T, fc2_b);
}